// Round 3
// baseline (954.831 us; speedup 1.0000x reference)
//
#include <hip/hip_runtime.h>

#define B_  2
#define S_  2048
#define D_  2048
#define H_  16
#define HD_ 128

typedef __bf16 bf16;
typedef __bf16 bf16x4 __attribute__((ext_vector_type(4)));
typedef __bf16 bf16x8 __attribute__((ext_vector_type(8)));
typedef float  f32x4  __attribute__((ext_vector_type(4)));

// =================== GEMM: C[m,n] = sum_k A[m,k]*W[n,k] ===================
// MODE 0: A = x (f32, split hi/lo), W = {qm|km|vm}*sw (bf16-exact).
//         q,k sections: split-A (2 MFMAs), epilogue stores hi/lo bf16 planes.
//         v section: single bf16 pass, epilogue stores bf16 plane.
// MODE 1: A = attn_out (bf16), W = om*sw, epilogue f32 C.
#define BK  64
#define LDK 72

template<int MODE>
__global__ __launch_bounds__(256)
void gemm_nt(const void* __restrict__ Av,
             const float* __restrict__ B0, const float* __restrict__ B1,
             const float* __restrict__ B2,
             const float* __restrict__ swp, const float* __restrict__ hm,
             bf16* __restrict__ qh_, bf16* __restrict__ ql_,
             bf16* __restrict__ kh_, bf16* __restrict__ kl_,
             bf16* __restrict__ vp_, float* __restrict__ Cf) {
    const int K = D_;
    __shared__ bf16 Ah[128 * LDK];
    __shared__ bf16 Al[128 * LDK];
    __shared__ bf16 Bs[128 * LDK];
    const int t = threadIdx.x;
    const int wave = t >> 6, lane = t & 63;
    const int wr = wave >> 1, wc = wave & 1;
    const int m0 = blockIdx.y * 128, n0 = blockIdx.x * 128;
    const int lrow = lane & 15, lquad = lane >> 4;
    const float sw = swp[0];

    const int which = (MODE == 0) ? (n0 >> 11) : 0;
    const bool split = (MODE == 0) && (which < 2);

    const float* Bp;
    if (MODE == 0) {
        Bp = (which == 0) ? B0 : ((which == 1) ? B1 : B2);
        Bp += (size_t)(n0 & (D_ - 1)) * K;
    } else {
        Bp = B0 + (size_t)n0 * K;
    }

    f32x4 acc[4][4];
#pragma unroll
    for (int i = 0; i < 4; i++)
#pragma unroll
        for (int j = 0; j < 4; j++) acc[i][j] = (f32x4){0.f, 0.f, 0.f, 0.f};

    for (int k0 = 0; k0 < K; k0 += BK) {
#pragma unroll
        for (int p = 0; p < 4; p++) {
            int idx = p * 256 + t;
            int row = idx >> 3;
            int col = (idx & 7) * 8;
            if (MODE == 0) {
                const float* ap = (const float*)Av + (size_t)(m0 + row) * K + k0 + col;
                float4 lo4 = *(const float4*)ap;
                float4 hi4 = *(const float4*)(ap + 4);
                float av[8] = {lo4.x, lo4.y, lo4.z, lo4.w, hi4.x, hi4.y, hi4.z, hi4.w};
                bf16x8 h8, l8;
#pragma unroll
                for (int e = 0; e < 8; e++) {
                    bf16 hv = (bf16)av[e];
                    h8[e] = hv;
                    l8[e] = (bf16)(av[e] - (float)hv);
                }
                *(bf16x8*)&Ah[row * LDK + col] = h8;
                if (split) *(bf16x8*)&Al[row * LDK + col] = l8;
            } else {
                *(bf16x8*)&Ah[row * LDK + col] =
                    *(const bf16x8*)((const bf16*)Av + (size_t)(m0 + row) * K + k0 + col);
            }
            const float* bp = Bp + (size_t)row * K + k0 + col;
            float4 blo = *(const float4*)bp;
            float4 bhi = *(const float4*)(bp + 4);
            bf16x8 b8;
            b8[0] = (bf16)(blo.x * sw); b8[1] = (bf16)(blo.y * sw);
            b8[2] = (bf16)(blo.z * sw); b8[3] = (bf16)(blo.w * sw);
            b8[4] = (bf16)(bhi.x * sw); b8[5] = (bf16)(bhi.y * sw);
            b8[6] = (bf16)(bhi.z * sw); b8[7] = (bf16)(bhi.w * sw);
            *(bf16x8*)&Bs[row * LDK + col] = b8;
        }
        __syncthreads();
#pragma unroll
        for (int kk = 0; kk < BK; kk += 32) {
            bf16x8 afh[4], afl[4], bfr[4];
#pragma unroll
            for (int i = 0; i < 4; i++) {
                afh[i] = *(const bf16x8*)&Ah[(wr * 64 + i * 16 + lrow) * LDK + kk + lquad * 8];
                if (split)
                    afl[i] = *(const bf16x8*)&Al[(wr * 64 + i * 16 + lrow) * LDK + kk + lquad * 8];
            }
#pragma unroll
            for (int j = 0; j < 4; j++)
                bfr[j] = *(const bf16x8*)&Bs[(wc * 64 + j * 16 + lrow) * LDK + kk + lquad * 8];
#pragma unroll
            for (int i = 0; i < 4; i++)
#pragma unroll
                for (int j = 0; j < 4; j++) {
                    acc[i][j] = __builtin_amdgcn_mfma_f32_16x16x32_bf16(
                        afh[i], bfr[j], acc[i][j], 0, 0, 0);
                    if (split)
                        acc[i][j] = __builtin_amdgcn_mfma_f32_16x16x32_bf16(
                            afl[i], bfr[j], acc[i][j], 0, 0, 0);
                }
        }
        __syncthreads();
    }

#pragma unroll
    for (int i = 0; i < 4; i++) {
#pragma unroll
        for (int j = 0; j < 4; j++) {
#pragma unroll
            for (int r = 0; r < 4; r++) {
                int m = m0 + wr * 64 + i * 16 + lquad * 4 + r;
                int n = n0 + wc * 64 + j * 16 + lrow;
                float v = acc[i][j][r];
                if (MODE == 0) {
                    int e = n & (D_ - 1);
                    int h = e >> 7, hd = e & (HD_ - 1);
                    int b = m >> 11, s = m & (S_ - 1);
                    v *= hm[h];
                    size_t idx = (((size_t)b * H_ + h) * S_ + s) * HD_ + hd;
                    if (which == 2) {
                        vp_[idx] = (bf16)v;
                    } else {
                        bf16 hv = (bf16)v;
                        bf16 lv = (bf16)(v - (float)hv);
                        if (which == 0) { qh_[idx] = hv; ql_[idx] = lv; }
                        else            { kh_[idx] = hv; kl_[idx] = lv; }
                    }
                } else {
                    Cf[(size_t)m * D_ + n] = v;
                }
            }
        }
    }
}

// =================== causal flash attention (MFMA, split QK) ===================
// grid: B*H*32 blocks, 256 threads. 64 q rows/block; wave w owns rows
// [w*16, w*16+16). Chunks of 64 k rows. Scores = qh*kh + qh*kl + ql*kh (fp32
// accurate: score err proportional to score gaps -> softmax-stable).
#define QLD 136
#define VLD 72

__global__ __launch_bounds__(256)
void attn_kernel(const bf16* __restrict__ qh_, const bf16* __restrict__ ql_,
                 const bf16* __restrict__ kh_, const bf16* __restrict__ kl_,
                 const bf16* __restrict__ v_, const float* __restrict__ am,
                 bf16* __restrict__ outp) {
    const int bh = blockIdx.x >> 5, qblk = blockIdx.x & 31;
    const int b = bh >> 4, h = bh & 15;
    const int i0 = qblk * 64;
    const int t = threadIdx.x, wave = t >> 6, lane = t & 63;
    const int lrow = lane & 15, quad = lane >> 4;

    __shared__ bf16 sqh[64 * QLD], sql[64 * QLD];
    __shared__ bf16 skh[64 * QLD], skl[64 * QLD];
    __shared__ bf16 svt[128 * VLD];            // V transposed: [d][j]
    __shared__ bf16 sp[4][16 * VLD];           // per-wave P strip

    const size_t base = (size_t)bh * S_ * HD_;

    // stage q tile once (hi+lo)
#pragma unroll
    for (int p = 0; p < 4; p++) {
        int idx = p * 256 + t;                 // 0..1023
        int r = idx >> 4;
        int c = (idx & 15) * 8;
        *(bf16x8*)&sqh[r * QLD + c] = *(const bf16x8*)&qh_[base + (size_t)(i0 + r) * HD_ + c];
        *(bf16x8*)&sql[r * QLD + c] = *(const bf16x8*)&ql_[base + (size_t)(i0 + r) * HD_ + c];
    }

    float m_i[4], l_i[4];
    f32x4 O[8];
#pragma unroll
    for (int r = 0; r < 4; r++) { m_i[r] = -INFINITY; l_i[r] = 0.f; }
#pragma unroll
    for (int n2 = 0; n2 < 8; n2++) O[n2] = (f32x4){0.f, 0.f, 0.f, 0.f};

    const float scale = 0.08838834764831845f;  // 1/sqrt(128)

    for (int j0 = 0; j0 <= i0; j0 += 64) {
        __syncthreads();
        // stage k chunk (hi+lo)
#pragma unroll
        for (int p = 0; p < 4; p++) {
            int idx = p * 256 + t;
            int r = idx >> 4;
            int c = (idx & 15) * 8;
            *(bf16x8*)&skh[r * QLD + c] = *(const bf16x8*)&kh_[base + (size_t)(j0 + r) * HD_ + c];
            *(bf16x8*)&skl[r * QLD + c] = *(const bf16x8*)&kl_[base + (size_t)(j0 + r) * HD_ + c];
        }
        // stage v chunk transposed
#pragma unroll
        for (int p = 0; p < 4; p++) {
            int idx = p * 256 + t;             // 0..1023
            int jr = idx & 63;
            int d0 = (idx >> 6) * 8;
            bf16x8 v8 = *(const bf16x8*)&v_[base + (size_t)(j0 + jr) * HD_ + d0];
#pragma unroll
            for (int e = 0; e < 8; e++) svt[(d0 + e) * VLD + jr] = v8[e];
        }
        __syncthreads();

        float amadd[4];
#pragma unroll
        for (int nt = 0; nt < 4; nt++)
            amadd[nt] = (1.0f - am[b * S_ + j0 + nt * 16 + lrow]) * -10000.0f;

        // QK^T: wave's 16 rows x 64 cols
        f32x4 s4[4];
#pragma unroll
        for (int nt = 0; nt < 4; nt++) s4[nt] = (f32x4){0.f, 0.f, 0.f, 0.f};
#pragma unroll
        for (int kk = 0; kk < 128; kk += 32) {
            bf16x8 ah = *(const bf16x8*)&sqh[(wave * 16 + lrow) * QLD + kk + quad * 8];
            bf16x8 al = *(const bf16x8*)&sql[(wave * 16 + lrow) * QLD + kk + quad * 8];
#pragma unroll
            for (int nt = 0; nt < 4; nt++) {
                bf16x8 bh8 = *(const bf16x8*)&skh[(nt * 16 + lrow) * QLD + kk + quad * 8];
                bf16x8 bl8 = *(const bf16x8*)&skl[(nt * 16 + lrow) * QLD + kk + quad * 8];
                s4[nt] = __builtin_amdgcn_mfma_f32_16x16x32_bf16(ah, bh8, s4[nt], 0, 0, 0);
                s4[nt] = __builtin_amdgcn_mfma_f32_16x16x32_bf16(ah, bl8, s4[nt], 0, 0, 0);
                s4[nt] = __builtin_amdgcn_mfma_f32_16x16x32_bf16(al, bh8, s4[nt], 0, 0, 0);
            }
        }

        const bool diag = (j0 == i0);
#pragma unroll
        for (int r = 0; r < 4; r++) {
            const int wrow = wave * 16 + quad * 4 + r;   // unused beyond diag test below
            const int rrow = quad * 4 + r;               // row within 64-block
            float sv[4], pw[4];
            float mx = -INFINITY;
#pragma unroll
            for (int nt = 0; nt < 4; nt++) {
                float xv = s4[nt][r] * scale + amadd[nt];
                if (diag && (nt * 16 + lrow) > rrow + wave * 16) xv = -INFINITY;
                sv[nt] = xv;
                mx = fmaxf(mx, xv);
            }
            (void)wrow;
#pragma unroll
            for (int off = 1; off < 16; off <<= 1) mx = fmaxf(mx, __shfl_xor(mx, off));
            float mnew = fmaxf(m_i[r], mx);
            float alpha = __expf(m_i[r] - mnew);
            float ps = 0.f;
#pragma unroll
            for (int nt = 0; nt < 4; nt++) { pw[nt] = __expf(sv[nt] - mnew); ps += pw[nt]; }
#pragma unroll
            for (int off = 1; off < 16; off <<= 1) ps += __shfl_xor(ps, off);
            l_i[r] = l_i[r] * alpha + ps;
            m_i[r] = mnew;
#pragma unroll
            for (int n2 = 0; n2 < 8; n2++) O[n2][r] *= alpha;
#pragma unroll
            for (int nt = 0; nt < 4; nt++)
                sp[wave][(quad * 4 + r) * VLD + nt * 16 + lrow] = (bf16)pw[nt];
        }
        __asm__ volatile("s_waitcnt lgkmcnt(0)" ::: "memory");

        // PV: O += P * V
#pragma unroll
        for (int kk2 = 0; kk2 < 64; kk2 += 32) {
            bf16x8 pf = *(const bf16x8*)&sp[wave][lrow * VLD + kk2 + quad * 8];
#pragma unroll
            for (int n2 = 0; n2 < 8; n2++) {
                bf16x8 vf8 = *(const bf16x8*)&svt[(n2 * 16 + lrow) * VLD + kk2 + quad * 8];
                O[n2] = __builtin_amdgcn_mfma_f32_16x16x32_bf16(pf, vf8, O[n2], 0, 0, 0);
            }
        }
    }

    float inv[4];
#pragma unroll
    for (int r = 0; r < 4; r++) inv[r] = 1.0f / l_i[r];
#pragma unroll
    for (int n2 = 0; n2 < 8; n2++)
#pragma unroll
        for (int r = 0; r < 4; r++) {
            int srow = i0 + wave * 16 + quad * 4 + r;
            outp[((size_t)(b * S_ + srow)) * D_ + h * HD_ + n2 * 16 + lrow] =
                (bf16)(O[n2][r] * inv[r]);
        }
}

// =================== launch ===================
extern "C" void kernel_launch(void* const* d_in, const int* in_sizes, int n_in,
                              void* d_out, int out_size, void* d_ws, size_t ws_size,
                              hipStream_t stream) {
    const float* x  = (const float*)d_in[0];
    const float* qm = (const float*)d_in[1];
    const float* km = (const float*)d_in[2];
    const float* vm = (const float*)d_in[3];
    const float* om = (const float*)d_in[4];
    const float* hm = (const float*)d_in[5];
    const float* am = (const float*)d_in[6];
    const float* sw = (const float*)d_in[7];
    float* out = (float*)d_out;

    // planes of [B,H,S,HD] bf16, 16 MiB each; total ws = 96 MiB
    const size_t P = (size_t)B_ * H_ * S_ * HD_ * sizeof(bf16);   // 16777216
    char* ws = (char*)d_ws;
    bf16* qh = (bf16*)(ws + 0 * P);
    bf16* ql = (bf16*)(ws + 1 * P);
    bf16* kh = (bf16*)(ws + 2 * P);
    bf16* kl = (bf16*)(ws + 3 * P);
    bf16* vp = (bf16*)(ws + 4 * P);
    bf16* attn_out = (bf16*)(ws + 5 * P);                          // [B*S, D] bf16

    // QKV projection, split-precision for q,k: M=4096, N=6144, K=2048
    gemm_nt<0><<<dim3(48, 32), 256, 0, stream>>>(
        (const void*)x, qm, km, vm, sw, hm, qh, ql, kh, kl, vp, nullptr);

    // attention
    attn_kernel<<<B_ * H_ * 32, 256, 0, stream>>>(qh, ql, kh, kl, vp, am, attn_out);

    // output projection: M=4096, N=2048, K=2048, f32 out
    gemm_nt<1><<<dim3(16, 32), 256, 0, stream>>>(
        (const void*)attn_out, om, nullptr, nullptr, sw, hm,
        nullptr, nullptr, nullptr, nullptr, nullptr, out);
}

// Round 4
// 691.192 us; speedup vs baseline: 1.3814x; 1.3814x over previous
//
#include <hip/hip_runtime.h>

#define B_  2
#define S_  2048
#define D_  2048
#define H_  16
#define HD_ 128

typedef __bf16 bf16;
typedef __bf16 bf16x4 __attribute__((ext_vector_type(4)));
typedef __bf16 bf16x8 __attribute__((ext_vector_type(8)));
typedef float  f32x4  __attribute__((ext_vector_type(4)));

// =================== GEMM: C[m,n] = sum_k A[m,k]*W[n,k] ===================
// MODE 0: A = x (f32, split hi/lo), W = {qm|km|vm}*sw (bf16-exact).
//         q,k sections: split-A (2 MFMAs), epilogue stores hi/lo bf16 planes.
//         v section: single bf16 pass, epilogue stores bf16 plane.
// MODE 1: A = attn_out (bf16), W = om*sw, epilogue f32 C.
#define BK  64
#define LDK 72

template<int MODE>
__global__ __launch_bounds__(256)
void gemm_nt(const void* __restrict__ Av,
             const float* __restrict__ B0, const float* __restrict__ B1,
             const float* __restrict__ B2,
             const float* __restrict__ swp, const float* __restrict__ hm,
             bf16* __restrict__ qh_, bf16* __restrict__ ql_,
             bf16* __restrict__ kh_, bf16* __restrict__ kl_,
             bf16* __restrict__ vp_, float* __restrict__ Cf) {
    const int K = D_;
    __shared__ bf16 Ah[128 * LDK];
    __shared__ bf16 Al[128 * LDK];
    __shared__ bf16 Bs[128 * LDK];
    const int t = threadIdx.x;
    const int wave = t >> 6, lane = t & 63;
    const int wr = wave >> 1, wc = wave & 1;
    const int m0 = blockIdx.y * 128, n0 = blockIdx.x * 128;
    const int lrow = lane & 15, lquad = lane >> 4;
    const float sw = swp[0];

    const int which = (MODE == 0) ? (n0 >> 11) : 0;
    const bool split = (MODE == 0) && (which < 2);

    const float* Bp;
    if (MODE == 0) {
        Bp = (which == 0) ? B0 : ((which == 1) ? B1 : B2);
        Bp += (size_t)(n0 & (D_ - 1)) * K;
    } else {
        Bp = B0 + (size_t)n0 * K;
    }

    f32x4 acc[4][4];
#pragma unroll
    for (int i = 0; i < 4; i++)
#pragma unroll
        for (int j = 0; j < 4; j++) acc[i][j] = (f32x4){0.f, 0.f, 0.f, 0.f};

    for (int k0 = 0; k0 < K; k0 += BK) {
#pragma unroll
        for (int p = 0; p < 4; p++) {
            int idx = p * 256 + t;
            int row = idx >> 3;
            int col = (idx & 7) * 8;
            if (MODE == 0) {
                const float* ap = (const float*)Av + (size_t)(m0 + row) * K + k0 + col;
                float4 lo4 = *(const float4*)ap;
                float4 hi4 = *(const float4*)(ap + 4);
                float av[8] = {lo4.x, lo4.y, lo4.z, lo4.w, hi4.x, hi4.y, hi4.z, hi4.w};
                bf16x8 h8, l8;
#pragma unroll
                for (int e = 0; e < 8; e++) {
                    bf16 hv = (bf16)av[e];
                    h8[e] = hv;
                    l8[e] = (bf16)(av[e] - (float)hv);
                }
                *(bf16x8*)&Ah[row * LDK + col] = h8;
                if (split) *(bf16x8*)&Al[row * LDK + col] = l8;
            } else {
                *(bf16x8*)&Ah[row * LDK + col] =
                    *(const bf16x8*)((const bf16*)Av + (size_t)(m0 + row) * K + k0 + col);
            }
            const float* bp = Bp + (size_t)row * K + k0 + col;
            float4 blo = *(const float4*)bp;
            float4 bhi = *(const float4*)(bp + 4);
            bf16x8 b8;
            b8[0] = (bf16)(blo.x * sw); b8[1] = (bf16)(blo.y * sw);
            b8[2] = (bf16)(blo.z * sw); b8[3] = (bf16)(blo.w * sw);
            b8[4] = (bf16)(bhi.x * sw); b8[5] = (bf16)(bhi.y * sw);
            b8[6] = (bf16)(bhi.z * sw); b8[7] = (bf16)(bhi.w * sw);
            *(bf16x8*)&Bs[row * LDK + col] = b8;
        }
        __syncthreads();
#pragma unroll
        for (int kk = 0; kk < BK; kk += 32) {
            bf16x8 afh[4], afl[4], bfr[4];
#pragma unroll
            for (int i = 0; i < 4; i++) {
                afh[i] = *(const bf16x8*)&Ah[(wr * 64 + i * 16 + lrow) * LDK + kk + lquad * 8];
                if (split)
                    afl[i] = *(const bf16x8*)&Al[(wr * 64 + i * 16 + lrow) * LDK + kk + lquad * 8];
            }
#pragma unroll
            for (int j = 0; j < 4; j++)
                bfr[j] = *(const bf16x8*)&Bs[(wc * 64 + j * 16 + lrow) * LDK + kk + lquad * 8];
#pragma unroll
            for (int i = 0; i < 4; i++)
#pragma unroll
                for (int j = 0; j < 4; j++) {
                    acc[i][j] = __builtin_amdgcn_mfma_f32_16x16x32_bf16(
                        afh[i], bfr[j], acc[i][j], 0, 0, 0);
                    if (split)
                        acc[i][j] = __builtin_amdgcn_mfma_f32_16x16x32_bf16(
                            afl[i], bfr[j], acc[i][j], 0, 0, 0);
                }
        }
        __syncthreads();
    }

#pragma unroll
    for (int i = 0; i < 4; i++) {
#pragma unroll
        for (int j = 0; j < 4; j++) {
#pragma unroll
            for (int r = 0; r < 4; r++) {
                int m = m0 + wr * 64 + i * 16 + lquad * 4 + r;
                int n = n0 + wc * 64 + j * 16 + lrow;
                float v = acc[i][j][r];
                if (MODE == 0) {
                    int e = n & (D_ - 1);
                    int h = e >> 7, hd = e & (HD_ - 1);
                    int b = m >> 11, s = m & (S_ - 1);
                    v *= hm[h];
                    size_t idx = (((size_t)b * H_ + h) * S_ + s) * HD_ + hd;
                    if (which == 2) {
                        vp_[idx] = (bf16)v;
                    } else {
                        bf16 hv = (bf16)v;
                        bf16 lv = (bf16)(v - (float)hv);
                        if (which == 0) { qh_[idx] = hv; ql_[idx] = lv; }
                        else            { kh_[idx] = hv; kl_[idx] = lv; }
                    }
                } else {
                    Cf[(size_t)m * D_ + n] = v;
                }
            }
        }
    }
}

// =================== causal flash attention (MFMA, split QK) ===================
// 64 q rows/block (wave w owns rows w*16..w*16+15, held as A-frags in REGISTERS,
// hi+lo). K chunks of 64 rows staged hi/lo in LDS; V staged transposed.
// LDS = 62464 B -> 2 blocks/CU. qblk reversed so longest blocks dispatch first.
#define KLD 136   // 128 + 8 pad (272 B row stride, 16B aligned)
#define VLD 72    // 64 + 8 pad

__global__ __launch_bounds__(256, 2)
void attn_kernel(const bf16* __restrict__ qh_, const bf16* __restrict__ ql_,
                 const bf16* __restrict__ kh_, const bf16* __restrict__ kl_,
                 const bf16* __restrict__ v_, const float* __restrict__ am,
                 bf16* __restrict__ outp) {
    const int bh = blockIdx.x & 31;
    const int qblk = 31 - (blockIdx.x >> 5);
    const int b = bh >> 4, h = bh & 15;
    const int i0 = qblk * 64;
    const int t = threadIdx.x, wave = t >> 6, lane = t & 63;
    const int lrow = lane & 15, quad = lane >> 4;

    __shared__ bf16 skh[64 * KLD], skl[64 * KLD];   // 17408 B each
    __shared__ bf16 svt[128 * VLD];                 // 18432 B  V^T: [d][j]
    __shared__ bf16 sp[4][16 * VLD];                // 9216 B   per-wave P strip

    const size_t base = (size_t)bh * S_ * HD_;

    // Q fragments (hi+lo) straight to registers: wave's 16 rows x 128 d
    const int qrow = i0 + wave * 16 + lrow;
    bf16x8 qhf[4], qlf[4];
#pragma unroll
    for (int c = 0; c < 4; c++) {
        qhf[c] = *(const bf16x8*)&qh_[base + (size_t)qrow * HD_ + c * 32 + quad * 8];
        qlf[c] = *(const bf16x8*)&ql_[base + (size_t)qrow * HD_ + c * 32 + quad * 8];
    }

    float m_i[4], l_i[4];
    f32x4 O[8];
#pragma unroll
    for (int r = 0; r < 4; r++) { m_i[r] = -INFINITY; l_i[r] = 0.f; }
#pragma unroll
    for (int n2 = 0; n2 < 8; n2++) O[n2] = (f32x4){0.f, 0.f, 0.f, 0.f};

    const float scale = 0.08838834764831845f;  // 1/sqrt(128)

    for (int j0 = 0; j0 <= i0; j0 += 64) {
        __syncthreads();
        // stage K chunk (hi+lo), vectorized b128
#pragma unroll
        for (int p = 0; p < 4; p++) {
            int idx = p * 256 + t;
            int r = idx >> 4;
            int c8 = (idx & 15) * 8;
            *(bf16x8*)&skh[r * KLD + c8] = *(const bf16x8*)&kh_[base + (size_t)(j0 + r) * HD_ + c8];
            *(bf16x8*)&skl[r * KLD + c8] = *(const bf16x8*)&kl_[base + (size_t)(j0 + r) * HD_ + c8];
        }
        // stage V chunk transposed: [d][j]
#pragma unroll
        for (int p = 0; p < 4; p++) {
            int d0 = (p * 4 + wave) * 8;
            bf16x8 v8 = *(const bf16x8*)&v_[base + (size_t)(j0 + lane) * HD_ + d0];
#pragma unroll
            for (int e = 0; e < 8; e++) svt[(d0 + e) * VLD + lane] = v8[e];
        }
        __syncthreads();

        float amadd[4];
#pragma unroll
        for (int nt = 0; nt < 4; nt++)
            amadd[nt] = (1.0f - am[b * S_ + j0 + nt * 16 + lrow]) * -10000.0f;

        // QK^T: wave's 16 rows x 64 cols, split 3-MFMA
        f32x4 s4[4];
#pragma unroll
        for (int nt = 0; nt < 4; nt++) s4[nt] = (f32x4){0.f, 0.f, 0.f, 0.f};
#pragma unroll
        for (int c = 0; c < 4; c++) {
#pragma unroll
            for (int nt = 0; nt < 4; nt++) {
                bf16x8 bh8 = *(const bf16x8*)&skh[(nt * 16 + lrow) * KLD + c * 32 + quad * 8];
                bf16x8 bl8 = *(const bf16x8*)&skl[(nt * 16 + lrow) * KLD + c * 32 + quad * 8];
                s4[nt] = __builtin_amdgcn_mfma_f32_16x16x32_bf16(qhf[c], bh8, s4[nt], 0, 0, 0);
                s4[nt] = __builtin_amdgcn_mfma_f32_16x16x32_bf16(qhf[c], bl8, s4[nt], 0, 0, 0);
                s4[nt] = __builtin_amdgcn_mfma_f32_16x16x32_bf16(qlf[c], bh8, s4[nt], 0, 0, 0);
            }
        }

        const bool diag = (j0 == i0);
#pragma unroll
        for (int r = 0; r < 4; r++) {
            const int rrow = wave * 16 + quad * 4 + r;   // row within 64-block
            float sv[4], pw[4];
            float mx = -INFINITY;
#pragma unroll
            for (int nt = 0; nt < 4; nt++) {
                float xv = s4[nt][r] * scale + amadd[nt];
                if (diag && (nt * 16 + lrow) > rrow) xv = -INFINITY;
                sv[nt] = xv;
                mx = fmaxf(mx, xv);
            }
#pragma unroll
            for (int off = 1; off < 16; off <<= 1) mx = fmaxf(mx, __shfl_xor(mx, off));
            float mnew = fmaxf(m_i[r], mx);
            float alpha = __expf(m_i[r] - mnew);
            float ps = 0.f;
#pragma unroll
            for (int nt = 0; nt < 4; nt++) { pw[nt] = __expf(sv[nt] - mnew); ps += pw[nt]; }
#pragma unroll
            for (int off = 1; off < 16; off <<= 1) ps += __shfl_xor(ps, off);
            l_i[r] = l_i[r] * alpha + ps;
            m_i[r] = mnew;
#pragma unroll
            for (int n2 = 0; n2 < 8; n2++) O[n2][r] *= alpha;
#pragma unroll
            for (int nt = 0; nt < 4; nt++)
                sp[wave][(quad * 4 + r) * VLD + nt * 16 + lrow] = (bf16)pw[nt];
        }
        __asm__ volatile("s_waitcnt lgkmcnt(0)" ::: "memory");   // sp is per-wave: no barrier

        // PV: O += P * V
#pragma unroll
        for (int kk2 = 0; kk2 < 64; kk2 += 32) {
            bf16x8 pf = *(const bf16x8*)&sp[wave][lrow * VLD + kk2 + quad * 8];
#pragma unroll
            for (int n2 = 0; n2 < 8; n2++) {
                bf16x8 vf8 = *(const bf16x8*)&svt[(n2 * 16 + lrow) * VLD + kk2 + quad * 8];
                O[n2] = __builtin_amdgcn_mfma_f32_16x16x32_bf16(pf, vf8, O[n2], 0, 0, 0);
            }
        }
    }

    float inv[4];
#pragma unroll
    for (int r = 0; r < 4; r++) inv[r] = 1.0f / l_i[r];
#pragma unroll
    for (int n2 = 0; n2 < 8; n2++)
#pragma unroll
        for (int r = 0; r < 4; r++) {
            int srow = i0 + wave * 16 + quad * 4 + r;
            outp[((size_t)(b * S_ + srow)) * D_ + h * HD_ + n2 * 16 + lrow] =
                (bf16)(O[n2][r] * inv[r]);
        }
}

// =================== launch ===================
extern "C" void kernel_launch(void* const* d_in, const int* in_sizes, int n_in,
                              void* d_out, int out_size, void* d_ws, size_t ws_size,
                              hipStream_t stream) {
    const float* x  = (const float*)d_in[0];
    const float* qm = (const float*)d_in[1];
    const float* km = (const float*)d_in[2];
    const float* vm = (const float*)d_in[3];
    const float* om = (const float*)d_in[4];
    const float* hm = (const float*)d_in[5];
    const float* am = (const float*)d_in[6];
    const float* sw = (const float*)d_in[7];
    float* out = (float*)d_out;

    // planes of [B,H,S,HD] bf16, 16 MiB each; total ws = 96 MiB
    const size_t P = (size_t)B_ * H_ * S_ * HD_ * sizeof(bf16);   // 16777216
    char* ws = (char*)d_ws;
    bf16* qh = (bf16*)(ws + 0 * P);
    bf16* ql = (bf16*)(ws + 1 * P);
    bf16* kh = (bf16*)(ws + 2 * P);
    bf16* kl = (bf16*)(ws + 3 * P);
    bf16* vp = (bf16*)(ws + 4 * P);
    bf16* attn_out = (bf16*)(ws + 5 * P);                          // [B*S, D] bf16

    // QKV projection, split-precision for q,k: M=4096, N=6144, K=2048
    gemm_nt<0><<<dim3(48, 32), 256, 0, stream>>>(
        (const void*)x, qm, km, vm, sw, hm, qh, ql, kh, kl, vp, nullptr);

    // attention
    attn_kernel<<<B_ * H_ * 32, 256, 0, stream>>>(qh, ql, kh, kl, vp, am, attn_out);

    // output projection: M=4096, N=2048, K=2048, f32 out
    gemm_nt<1><<<dim3(16, 32), 256, 0, stream>>>(
        (const void*)attn_out, om, nullptr, nullptr, sw, hm,
        nullptr, nullptr, nullptr, nullptr, nullptr, out);
}

// Round 5
// 508.739 us; speedup vs baseline: 1.8769x; 1.3586x over previous
//
#include <hip/hip_runtime.h>

#define B_  2
#define S_  2048
#define D_  2048
#define H_  16
#define HD_ 128

typedef __bf16 bf16;
typedef __bf16 bf16x4 __attribute__((ext_vector_type(4)));
typedef __bf16 bf16x8 __attribute__((ext_vector_type(8)));
typedef float  f32x4  __attribute__((ext_vector_type(4)));

// async global->LDS 16B copy: lds dst = wave-uniform base + lane*16
__device__ __forceinline__ void gld_lds16(const void* g, void* l) {
    __builtin_amdgcn_global_load_lds(
        (const __attribute__((address_space(1))) unsigned int*)g,
        (__attribute__((address_space(3))) unsigned int*)l, 16, 0, 0);
}

// ---------------- precast: x f32 -> hi/lo bf16 planes ----------------
__global__ __launch_bounds__(256)
void precast_kernel(const float* __restrict__ x, bf16* __restrict__ xh,
                    bf16* __restrict__ xl) {
    int i = (blockIdx.x * 256 + threadIdx.x) * 8;
    float4 a = *(const float4*)(x + i);
    float4 b = *(const float4*)(x + i + 4);
    float av[8] = {a.x, a.y, a.z, a.w, b.x, b.y, b.z, b.w};
    bf16x8 h8, l8;
#pragma unroll
    for (int e = 0; e < 8; e++) {
        bf16 hv = (bf16)av[e];
        h8[e] = hv;
        l8[e] = (bf16)(av[e] - (float)hv);
    }
    *(bf16x8*)(xh + i) = h8;
    *(bf16x8*)(xl + i) = l8;
}

// =================== GEMM: C[m,n] = sum_k A[m,k]*W[n,k] ===================
// A planes are bf16 in global (hi + optional lo), staged via global_load_lds
// with XOR-swizzled columns (phys_group = log_group ^ (row&7)); no LDS pad.
// B (masks) is f32, VALU-staged (mul sw + cvt) into the same swizzled layout.
// MODE 0: split A (xh,xl), sections q|k|v; epilogue *hm, scatter planes.
// MODE 1: single A (attn_out); epilogue f32.
#define BK 64

template<int MODE>
__global__ __launch_bounds__(256, 3)
void gemm_nt(const bf16* __restrict__ Ah_g, const bf16* __restrict__ Al_g,
             const float* __restrict__ B0, const float* __restrict__ B1,
             const float* __restrict__ B2,
             const float* __restrict__ swp, const float* __restrict__ hm,
             bf16* __restrict__ qh_, bf16* __restrict__ ql_,
             bf16* __restrict__ kh_, bf16* __restrict__ kl_,
             bf16* __restrict__ vp_, float* __restrict__ Cf) {
    const int K = D_;
    __shared__ bf16 Ah[128 * 64];
    __shared__ bf16 Al[128 * 64];
    __shared__ bf16 Bs[128 * 64];
    const int t = threadIdx.x;
    const int wave = t >> 6, lane = t & 63;
    const int wr = wave >> 1, wc = wave & 1;
    const int m0 = blockIdx.y * 128, n0 = blockIdx.x * 128;
    const int lrow = lane & 15, lquad = lane >> 4;
    const float sw = swp[0];

    const int which = (MODE == 0) ? (n0 >> 11) : 0;
    const bool split = (MODE == 0) && (which < 2);

    const float* Bp;
    if (MODE == 0) {
        Bp = (which == 0) ? B0 : ((which == 1) ? B1 : B2);
        Bp += (size_t)(n0 & (D_ - 1)) * K;
    } else {
        Bp = B0 + (size_t)n0 * K;
    }

    // staging geometry
    const int srow8 = lane >> 3;          // 0..7 (row within 8-row group)
    const int sgrp  = lane & 7;           // phys 16B-group
    // frag-read swizzled groups (per lane)
    const int g0 = (lquad)     ^ (lrow & 7);   // kk = 0
    const int g1 = (lquad + 4) ^ (lrow & 7);   // kk = 32

    f32x4 acc[4][4];
#pragma unroll
    for (int i = 0; i < 4; i++)
#pragma unroll
        for (int j = 0; j < 4; j++) acc[i][j] = (f32x4){0.f, 0.f, 0.f, 0.f};

    for (int k0 = 0; k0 < K; k0 += BK) {
        // ---- A: async global->LDS, XOR swizzle on source column ----
#pragma unroll
        for (int p = 0; p < 4; p++) {
            int r = wave * 32 + p * 8 + srow8;
            int gcol = (sgrp ^ (r & 7)) * 8;
            gld_lds16(Ah_g + (size_t)(m0 + r) * K + k0 + gcol,
                      &Ah[(wave * 32 + p * 8) * 64]);
            if (split)
                gld_lds16(Al_g + (size_t)(m0 + r) * K + k0 + gcol,
                          &Al[(wave * 32 + p * 8) * 64]);
        }
        // ---- B: f32 load + scale + cvt, swizzled ds_write_b128 ----
#pragma unroll
        for (int p = 0; p < 4; p++) {
            int r = p * 32 + (t >> 3);
            int gcol = (sgrp ^ (r & 7)) * 8;
            const float* bp = Bp + (size_t)r * K + k0 + gcol;
            float4 blo = *(const float4*)bp;
            float4 bhi = *(const float4*)(bp + 4);
            bf16x8 b8;
            b8[0] = (bf16)(blo.x * sw); b8[1] = (bf16)(blo.y * sw);
            b8[2] = (bf16)(blo.z * sw); b8[3] = (bf16)(blo.w * sw);
            b8[4] = (bf16)(bhi.x * sw); b8[5] = (bf16)(bhi.y * sw);
            b8[6] = (bf16)(bhi.z * sw); b8[7] = (bf16)(bhi.w * sw);
            *(bf16x8*)&Bs[r * 64 + sgrp * 8] = b8;
        }
        __syncthreads();   // drains vmcnt (global_load_lds) + lgkm

        // ---- MFMA over kk = 0, 32 ----
#pragma unroll
        for (int kk = 0; kk < 2; kk++) {
            const int gA = kk ? g1 : g0;
            bf16x8 afh[4], afl[4], bfr[4];
#pragma unroll
            for (int i = 0; i < 4; i++) {
                int row = wr * 64 + i * 16 + lrow;
                afh[i] = *(const bf16x8*)&Ah[row * 64 + gA * 8];
                if (split) afl[i] = *(const bf16x8*)&Al[row * 64 + gA * 8];
            }
#pragma unroll
            for (int j = 0; j < 4; j++) {
                int row = wc * 64 + j * 16 + lrow;
                bfr[j] = *(const bf16x8*)&Bs[row * 64 + gA * 8];
            }
#pragma unroll
            for (int i = 0; i < 4; i++)
#pragma unroll
                for (int j = 0; j < 4; j++) {
                    acc[i][j] = __builtin_amdgcn_mfma_f32_16x16x32_bf16(
                        afh[i], bfr[j], acc[i][j], 0, 0, 0);
                    if (split)
                        acc[i][j] = __builtin_amdgcn_mfma_f32_16x16x32_bf16(
                            afl[i], bfr[j], acc[i][j], 0, 0, 0);
                }
        }
        __syncthreads();
    }

#pragma unroll
    for (int i = 0; i < 4; i++) {
#pragma unroll
        for (int j = 0; j < 4; j++) {
#pragma unroll
            for (int r = 0; r < 4; r++) {
                int m = m0 + wr * 64 + i * 16 + lquad * 4 + r;
                int n = n0 + wc * 64 + j * 16 + lrow;
                float v = acc[i][j][r];
                if (MODE == 0) {
                    int e = n & (D_ - 1);
                    int h = e >> 7, hd = e & (HD_ - 1);
                    int b = m >> 11, s = m & (S_ - 1);
                    v *= hm[h];
                    size_t idx = (((size_t)b * H_ + h) * S_ + s) * HD_ + hd;
                    if (which == 2) {
                        vp_[idx] = (bf16)v;
                    } else {
                        bf16 hv = (bf16)v;
                        bf16 lv = (bf16)(v - (float)hv);
                        if (which == 0) { qh_[idx] = hv; ql_[idx] = lv; }
                        else            { kh_[idx] = hv; kl_[idx] = lv; }
                    }
                } else {
                    Cf[(size_t)m * D_ + n] = v;
                }
            }
        }
    }
}

// =================== causal flash attention (MFMA, split QK) ===================
#define KLD 136   // 128 + 8 pad
#define VLD 72    // 64 + 8 pad

__global__ __launch_bounds__(256, 2)
void attn_kernel(const bf16* __restrict__ qh_, const bf16* __restrict__ ql_,
                 const bf16* __restrict__ kh_, const bf16* __restrict__ kl_,
                 const bf16* __restrict__ v_, const float* __restrict__ am,
                 bf16* __restrict__ outp) {
    const int bh = blockIdx.x & 31;
    const int qblk = 31 - (blockIdx.x >> 5);
    const int b = bh >> 4, h = bh & 15;
    const int i0 = qblk * 64;
    const int t = threadIdx.x, wave = t >> 6, lane = t & 63;
    const int lrow = lane & 15, quad = lane >> 4;

    __shared__ bf16 skh[64 * KLD], skl[64 * KLD];
    __shared__ bf16 svt[128 * VLD];            // V^T: [d][j]
    __shared__ bf16 sp[4][16 * VLD];           // per-wave P strip

    const size_t base = (size_t)bh * S_ * HD_;

    const int qrow = i0 + wave * 16 + lrow;
    bf16x8 qhf[4], qlf[4];
#pragma unroll
    for (int c = 0; c < 4; c++) {
        qhf[c] = *(const bf16x8*)&qh_[base + (size_t)qrow * HD_ + c * 32 + quad * 8];
        qlf[c] = *(const bf16x8*)&ql_[base + (size_t)qrow * HD_ + c * 32 + quad * 8];
    }

    float m_i[4], l_i[4];
    f32x4 O[8];
#pragma unroll
    for (int r = 0; r < 4; r++) { m_i[r] = -INFINITY; l_i[r] = 0.f; }
#pragma unroll
    for (int n2 = 0; n2 < 8; n2++) O[n2] = (f32x4){0.f, 0.f, 0.f, 0.f};

    const float scale = 0.08838834764831845f;  // 1/sqrt(128)

    for (int j0 = 0; j0 <= i0; j0 += 64) {
        __syncthreads();
#pragma unroll
        for (int p = 0; p < 4; p++) {
            int idx = p * 256 + t;
            int r = idx >> 4;
            int c8 = (idx & 15) * 8;
            *(bf16x8*)&skh[r * KLD + c8] = *(const bf16x8*)&kh_[base + (size_t)(j0 + r) * HD_ + c8];
            *(bf16x8*)&skl[r * KLD + c8] = *(const bf16x8*)&kl_[base + (size_t)(j0 + r) * HD_ + c8];
        }
#pragma unroll
        for (int p = 0; p < 4; p++) {
            int d0 = (p * 4 + wave) * 8;
            bf16x8 v8 = *(const bf16x8*)&v_[base + (size_t)(j0 + lane) * HD_ + d0];
#pragma unroll
            for (int e = 0; e < 8; e++) svt[(d0 + e) * VLD + lane] = v8[e];
        }
        __syncthreads();

        float amadd[4];
#pragma unroll
        for (int nt = 0; nt < 4; nt++)
            amadd[nt] = (1.0f - am[b * S_ + j0 + nt * 16 + lrow]) * -10000.0f;

        f32x4 s4[4];
#pragma unroll
        for (int nt = 0; nt < 4; nt++) s4[nt] = (f32x4){0.f, 0.f, 0.f, 0.f};
#pragma unroll
        for (int c = 0; c < 4; c++) {
#pragma unroll
            for (int nt = 0; nt < 4; nt++) {
                bf16x8 bh8 = *(const bf16x8*)&skh[(nt * 16 + lrow) * KLD + c * 32 + quad * 8];
                bf16x8 bl8 = *(const bf16x8*)&skl[(nt * 16 + lrow) * KLD + c * 32 + quad * 8];
                s4[nt] = __builtin_amdgcn_mfma_f32_16x16x32_bf16(qhf[c], bh8, s4[nt], 0, 0, 0);
                s4[nt] = __builtin_amdgcn_mfma_f32_16x16x32_bf16(qhf[c], bl8, s4[nt], 0, 0, 0);
                s4[nt] = __builtin_amdgcn_mfma_f32_16x16x32_bf16(qlf[c], bh8, s4[nt], 0, 0, 0);
            }
        }

        const bool diag = (j0 == i0);
#pragma unroll
        for (int r = 0; r < 4; r++) {
            const int rrow = wave * 16 + quad * 4 + r;
            float sv[4], pw[4];
            float mx = -INFINITY;
#pragma unroll
            for (int nt = 0; nt < 4; nt++) {
                float xv = s4[nt][r] * scale + amadd[nt];
                if (diag && (nt * 16 + lrow) > rrow) xv = -INFINITY;
                sv[nt] = xv;
                mx = fmaxf(mx, xv);
            }
#pragma unroll
            for (int off = 1; off < 16; off <<= 1) mx = fmaxf(mx, __shfl_xor(mx, off));
            float mnew = fmaxf(m_i[r], mx);
            float alpha = __expf(m_i[r] - mnew);
            float ps = 0.f;
#pragma unroll
            for (int nt = 0; nt < 4; nt++) { pw[nt] = __expf(sv[nt] - mnew); ps += pw[nt]; }
#pragma unroll
            for (int off = 1; off < 16; off <<= 1) ps += __shfl_xor(ps, off);
            l_i[r] = l_i[r] * alpha + ps;
            m_i[r] = mnew;
#pragma unroll
            for (int n2 = 0; n2 < 8; n2++) O[n2][r] *= alpha;
#pragma unroll
            for (int nt = 0; nt < 4; nt++)
                sp[wave][(quad * 4 + r) * VLD + nt * 16 + lrow] = (bf16)pw[nt];
        }
        __asm__ volatile("s_waitcnt lgkmcnt(0)" ::: "memory");   // sp per-wave

#pragma unroll
        for (int kk2 = 0; kk2 < 64; kk2 += 32) {
            bf16x8 pf = *(const bf16x8*)&sp[wave][lrow * VLD + kk2 + quad * 8];
#pragma unroll
            for (int n2 = 0; n2 < 8; n2++) {
                bf16x8 vf8 = *(const bf16x8*)&svt[(n2 * 16 + lrow) * VLD + kk2 + quad * 8];
                O[n2] = __builtin_amdgcn_mfma_f32_16x16x32_bf16(pf, vf8, O[n2], 0, 0, 0);
            }
        }
    }

    float inv[4];
#pragma unroll
    for (int r = 0; r < 4; r++) inv[r] = 1.0f / l_i[r];
#pragma unroll
    for (int n2 = 0; n2 < 8; n2++)
#pragma unroll
        for (int r = 0; r < 4; r++) {
            int srow = i0 + wave * 16 + quad * 4 + r;
            outp[((size_t)(b * S_ + srow)) * D_ + h * HD_ + n2 * 16 + lrow] =
                (bf16)(O[n2][r] * inv[r]);
        }
}

// =================== launch ===================
extern "C" void kernel_launch(void* const* d_in, const int* in_sizes, int n_in,
                              void* d_out, int out_size, void* d_ws, size_t ws_size,
                              hipStream_t stream) {
    const float* x  = (const float*)d_in[0];
    const float* qm = (const float*)d_in[1];
    const float* km = (const float*)d_in[2];
    const float* vm = (const float*)d_in[3];
    const float* om = (const float*)d_in[4];
    const float* hm = (const float*)d_in[5];
    const float* am = (const float*)d_in[6];
    const float* sw = (const float*)d_in[7];
    float* out = (float*)d_out;

    // ws layout (96 MiB): [xh 16M | xl 16M | qh 16M | ql 16M | kh 16M | kl 16M]
    // vp lives in d_out (free until gemm1 overwrites); attn_out overlays xh.
    const size_t P = (size_t)B_ * H_ * S_ * HD_ * sizeof(bf16);   // 16777216
    char* ws = (char*)d_ws;
    bf16* xh = (bf16*)(ws + 0 * P);
    bf16* xl = (bf16*)(ws + 1 * P);
    bf16* qh = (bf16*)(ws + 2 * P);
    bf16* ql = (bf16*)(ws + 3 * P);
    bf16* kh = (bf16*)(ws + 4 * P);
    bf16* kl = (bf16*)(ws + 5 * P);
    bf16* vp = (bf16*)d_out;                    // 16 MiB of d_out's 32 MiB
    bf16* attn_out = (bf16*)(ws + 0 * P);       // overlays xh/xl after gemm0

    // precast x -> hi/lo bf16 planes
    precast_kernel<<<(B_ * S_ * D_) / (256 * 8), 256, 0, stream>>>(x, xh, xl);

    // QKV projection, split-precision q,k: M=4096, N=6144, K=2048
    gemm_nt<0><<<dim3(48, 32), 256, 0, stream>>>(
        xh, xl, qm, km, vm, sw, hm, qh, ql, kh, kl, vp, nullptr);

    // attention
    attn_kernel<<<B_ * H_ * 32, 256, 0, stream>>>(qh, ql, kh, kl, vp, am, attn_out);

    // output projection: M=4096, N=2048, K=2048, f32 out
    gemm_nt<1><<<dim3(16, 32), 256, 0, stream>>>(
        attn_out, nullptr, om, nullptr, nullptr, sw, hm,
        nullptr, nullptr, nullptr, nullptr, nullptr, out);
}